// Round 7
// baseline (417.728 us; speedup 1.0000x reference)
//
#include <hip/hip_runtime.h>
#include <hip/hip_bf16.h>

typedef unsigned int u32;
typedef unsigned short u16;
typedef _Float16 f16x2 __attribute__((ext_vector_type(2)));
typedef _Float16 f16x8 __attribute__((ext_vector_type(8)));
typedef float f32x4 __attribute__((ext_vector_type(4)));

#define NN 50000
#define EE 800000
#define A1_BLOCKS 4096
#define SCAN_B ((NN + 255) / 256)     // 196
#define G1_TILES (((NN + 63) / 64) * 2)   // 1564 gemm1 blocks (BN=128, Nc=256)
#define CNT_B ((EE + 255) / 256)      // 3125 count blocks

__device__ __forceinline__ f16x2 ash(u32 u) { union { u32 u; f16x2 h; } c; c.u = u; return c.h; }
__device__ __forceinline__ u32 h2u(f16x2 h) { union { u32 u; f16x2 h; } c; c.h = h; return c.u; }
__device__ __forceinline__ u16 f2h(float v) { _Float16 h = (_Float16)v; return *(u16*)&h; }
__device__ __forceinline__ u32 pack2h(float a, float b) {
    return (u32)f2h(a) | ((u32)f2h(b) << 16);
}
__device__ __forceinline__ float elu(float v) { return v > 0.f ? v : __expf(v) - 1.f; }

// ---------------- prep: weight transpose->f16 (blocks 0-575) + deg zero (blocks 576+) ----------------

__global__ __launch_bounds__(256) void gat_prep_r24(const float* __restrict__ W1,
                                                    const float* __restrict__ W2,
                                                    const float* __restrict__ W3,
                                                    u16* __restrict__ W1t,
                                                    u16* __restrict__ W2t,
                                                    u16* __restrict__ W3t,
                                                    int* __restrict__ deg) {
    int b = blockIdx.x, t = threadIdx.x;
    if (b < 256) {
        if (t < 128) W1t[(long)b * 128 + t] = f2h(W1[(long)t * 256 + b]);
    } else if (b < 512) {
        int n = b - 256;
        W2t[(long)n * 256 + t] = f2h(W2[(long)t * 256 + n]);
    } else if (b < 576) {
        int n = b - 512;
        W3t[(long)n * 256 + t] = f2h(W3[(long)t * 64 + n]);
    } else {
        int i = (b - 576) * 256 + t;
        if (i < NN) deg[i] = 0;
    }
}

// ---------------- MFMA GEMM BN=128 body (layer-1 fused kernel) ----------------

template <int AHF>
__device__ __forceinline__ void gemm128_body(const void* __restrict__ Ain,
                                             const u16* __restrict__ Wt,
                                             const float* __restrict__ bias,
                                             u16* __restrict__ C,
                                             int M, int K, int Nc,
                                             int bm, int bn) {
    __shared__ __align__(16) u16 As[64 * 40];
    __shared__ __align__(16) u16 Bs[128 * 40];
    const int t    = threadIdx.x;
    const int w    = t >> 6;
    const int lane = t & 63;
    const int sm   = t >> 2;
    const int sk   = (t & 3) * 8;
    const int fq   = (lane >> 4) * 8;
    const int fr   = lane & 15;
    const int nbase = w * 32;

    f32x4 acc[4][2] = {};

    for (int k0 = 0; k0 < K; k0 += 32) {
        {
            int gr = bm + sm;
            f16x8 av = {};
            if (gr < M) {
                if (AHF) {
                    av = *(const f16x8*)((const u16*)Ain + (long)gr * K + k0 + sk);
                } else {
                    const float* p = (const float*)Ain + (long)gr * K + k0 + sk;
                    #pragma unroll
                    for (int i = 0; i < 8; ++i) av[i] = (_Float16)p[i];
                }
            }
            *(f16x8*)&As[sm * 40 + sk] = av;
        }
        #pragma unroll
        for (int i = 0; i < 2; ++i) {
            int tau = t + i * 256;
            int row = tau >> 2, ck = (tau & 3) * 8;
            f16x8 bv = *(const f16x8*)(Wt + (long)(bn + row) * K + k0 + ck);
            *(f16x8*)&Bs[row * 40 + ck] = bv;
        }
        __syncthreads();
        f16x8 afr[4], bfr[2];
        #pragma unroll
        for (int mt = 0; mt < 4; ++mt)
            afr[mt] = *(const f16x8*)&As[(mt * 16 + fr) * 40 + fq];
        #pragma unroll
        for (int nt = 0; nt < 2; ++nt)
            bfr[nt] = *(const f16x8*)&Bs[(nbase + nt * 16 + fr) * 40 + fq];
        #pragma unroll
        for (int mt = 0; mt < 4; ++mt)
            #pragma unroll
            for (int nt = 0; nt < 2; ++nt)
                acc[mt][nt] = __builtin_amdgcn_mfma_f32_16x16x32_f16(
                    afr[mt], bfr[nt], acc[mt][nt], 0, 0, 0);
        __syncthreads();
    }
    #pragma unroll
    for (int mt = 0; mt < 4; ++mt) {
        #pragma unroll
        for (int r = 0; r < 4; ++r) {
            int row = bm + mt * 16 + (lane >> 4) * 4 + r;
            if (row >= M) continue;
            #pragma unroll
            for (int nt = 0; nt < 2; ++nt) {
                int col = bn + nbase + nt * 16 + fr;
                C[(long)row * Nc + col] = f2h(acc[mt][nt][r] + bias[col]);
            }
        }
    }
}

// ---------------- fused: layer-1 GEMM + degree count (independent, concurrent) ----------------

__global__ __launch_bounds__(256) void gat_fuse1_r24(const float* __restrict__ x,
                                                     const u16* __restrict__ W1t,
                                                     const float* __restrict__ b1,
                                                     u16* __restrict__ P,
                                                     const int* __restrict__ dst,
                                                     int* __restrict__ deg) {
    int b = blockIdx.x;
    if (b < G1_TILES) {
        int bm = (b >> 1) * 64;
        int bn = (b & 1) * 128;
        gemm128_body<0>(x, W1t, b1, P, NN, 128, 256, bm, bn);
    } else {
        int e = (b - G1_TILES) * 256 + threadIdx.x;
        if (e < EE) atomicAdd(&deg[dst[e]], 1);
    }
}

// ---------------- layer-2 GEMM: BM=64 x BN=256 single pass (A read once) ----------------

__global__ __launch_bounds__(256) void gat_gemm2_r24(const u16* __restrict__ Q,
                                                     const u16* __restrict__ W2t,
                                                     const float* __restrict__ b2,
                                                     u16* __restrict__ P) {
    __shared__ __align__(16) u16 As[64 * 40];
    __shared__ __align__(16) u16 Bs[256 * 40];
    const int t    = threadIdx.x;
    const int w    = t >> 6;
    const int lane = t & 63;
    const int sm   = t >> 2;
    const int sk   = (t & 3) * 8;
    const int fq   = (lane >> 4) * 8;
    const int fr   = lane & 15;
    const int nbase = w * 64;
    const int bm   = blockIdx.x * 64;

    f32x4 acc[4][4] = {};

    for (int k0 = 0; k0 < 256; k0 += 32) {
        {
            int gr = bm + sm;
            f16x8 av = {};
            if (gr < NN) av = *(const f16x8*)(Q + (long)gr * 256 + k0 + sk);
            *(f16x8*)&As[sm * 40 + sk] = av;
        }
        #pragma unroll
        for (int i = 0; i < 4; ++i) {
            int tau = t + i * 256;
            int row = tau >> 2, ck = (tau & 3) * 8;
            f16x8 bv = *(const f16x8*)(W2t + (long)row * 256 + k0 + ck);
            *(f16x8*)&Bs[row * 40 + ck] = bv;
        }
        __syncthreads();
        f16x8 afr[4], bfr[4];
        #pragma unroll
        for (int mt = 0; mt < 4; ++mt)
            afr[mt] = *(const f16x8*)&As[(mt * 16 + fr) * 40 + fq];
        #pragma unroll
        for (int nt = 0; nt < 4; ++nt)
            bfr[nt] = *(const f16x8*)&Bs[(nbase + nt * 16 + fr) * 40 + fq];
        #pragma unroll
        for (int mt = 0; mt < 4; ++mt)
            #pragma unroll
            for (int nt = 0; nt < 4; ++nt)
                acc[mt][nt] = __builtin_amdgcn_mfma_f32_16x16x32_f16(
                    afr[mt], bfr[nt], acc[mt][nt], 0, 0, 0);
        __syncthreads();
    }
    #pragma unroll
    for (int mt = 0; mt < 4; ++mt) {
        #pragma unroll
        for (int r = 0; r < 4; ++r) {
            int row = bm + mt * 16 + (lane >> 4) * 4 + r;
            if (row >= NN) continue;
            #pragma unroll
            for (int nt = 0; nt < 4; ++nt) {
                int col = nbase + nt * 16 + fr;
                P[(long)row * 256 + col] = f2h(acc[mt][nt][r] + b2[col]);
            }
        }
    }
}

// ---------------- CSR scan + scatter ----------------

__global__ __launch_bounds__(256) void gat_scana_r24(const int* __restrict__ deg,
                                                     int* __restrict__ bsum) {
    __shared__ int s[256];
    int t = threadIdx.x;
    int i = blockIdx.x * 256 + t;
    s[t] = (i < NN) ? deg[i] : 0;
    __syncthreads();
    for (int o = 128; o > 0; o >>= 1) {
        if (t < o) s[t] += s[t + o];
        __syncthreads();
    }
    if (t == 0) bsum[blockIdx.x] = s[0];
}

__global__ __launch_bounds__(256) void gat_scanc_r24(const int* __restrict__ deg,
                                                     const int* __restrict__ bsum,
                                                     int* __restrict__ row_ptr,
                                                     int* __restrict__ cursor) {
    __shared__ int sb[256];
    __shared__ int s[256];
    int t = threadIdx.x;
    sb[t] = (t < SCAN_B) ? bsum[t] : 0;
    __syncthreads();
    for (int o = 1; o < 256; o <<= 1) {
        int u = (t >= o) ? sb[t - o] : 0;
        __syncthreads();
        sb[t] += u;
        __syncthreads();
    }
    int boff = (blockIdx.x == 0) ? 0 : sb[blockIdx.x - 1];
    if (blockIdx.x == 0 && t == 0) row_ptr[NN] = sb[SCAN_B - 1];
    int i = blockIdx.x * 256 + t;
    int v = (i < NN) ? deg[i] : 0;
    s[t] = v;
    __syncthreads();
    for (int o = 1; o < 256; o <<= 1) {
        int u = (t >= o) ? s[t - o] : 0;
        __syncthreads();
        s[t] += u;
        __syncthreads();
    }
    if (i < NN) {
        int excl = s[t] - v + boff;
        row_ptr[i] = excl;
        cursor[i]  = excl;
    }
}

__global__ void gat_scatter_r24(const int* __restrict__ src, const int* __restrict__ dst,
                                int* __restrict__ cursor, int* __restrict__ esrc) {
    int e = blockIdx.x * 256 + threadIdx.x;
    if (e < EE) {
        int pos = atomicAdd(&cursor[dst[e]], 1);
        esrc[pos] = src[e];
    }
}

// ---------------- MFMA GEMM, BN=64 — layer 3 (Nc=64) ----------------

__global__ __launch_bounds__(256) void gat_gemm64_r24(const u16* __restrict__ Ain,
                                                      const u16* __restrict__ Wt,
                                                      const float* __restrict__ bias,
                                                      u16* __restrict__ C,
                                                      int M, int K, int Nc) {
    __shared__ __align__(16) u16 As[64 * 40];
    __shared__ __align__(16) u16 Bs[64 * 40];
    const int t    = threadIdx.x;
    const int bm   = blockIdx.x * 64;
    const int bn   = blockIdx.y * 64;
    const int w    = t >> 6;
    const int lane = t & 63;
    const int sm   = t >> 2;
    const int sk   = (t & 3) * 8;
    const int mbase = (w & 1) * 32;
    const int nbase = (w >> 1) * 32;
    const int fq    = (lane >> 4) * 8;
    const int fr    = lane & 15;

    f32x4 acc[2][2] = {};

    for (int k0 = 0; k0 < K; k0 += 32) {
        {
            int gr = bm + sm;
            f16x8 av = {};
            if (gr < M) av = *(const f16x8*)(Ain + (long)gr * K + k0 + sk);
            *(f16x8*)&As[sm * 40 + sk] = av;
        }
        {
            f16x8 bv = *(const f16x8*)(Wt + (long)(bn + sm) * K + k0 + sk);
            *(f16x8*)&Bs[sm * 40 + sk] = bv;
        }
        __syncthreads();
        f16x8 afr[2], bfr[2];
        #pragma unroll
        for (int mt = 0; mt < 2; ++mt)
            afr[mt] = *(const f16x8*)&As[(mbase + mt * 16 + fr) * 40 + fq];
        #pragma unroll
        for (int nt = 0; nt < 2; ++nt)
            bfr[nt] = *(const f16x8*)&Bs[(nbase + nt * 16 + fr) * 40 + fq];
        #pragma unroll
        for (int mt = 0; mt < 2; ++mt)
            #pragma unroll
            for (int nt = 0; nt < 2; ++nt)
                acc[mt][nt] = __builtin_amdgcn_mfma_f32_16x16x32_f16(
                    afr[mt], bfr[nt], acc[mt][nt], 0, 0, 0);
        __syncthreads();
    }
    #pragma unroll
    for (int mt = 0; mt < 2; ++mt) {
        #pragma unroll
        for (int r = 0; r < 4; ++r) {
            int row = bm + mbase + mt * 16 + (lane >> 4) * 4 + r;
            if (row >= M) continue;
            #pragma unroll
            for (int nt = 0; nt < 2; ++nt) {
                int col = bn + nbase + nt * 16 + fr;
                C[(long)row * Nc + col] = f2h(acc[mt][nt][r] + bias[col]);
            }
        }
    }
}

// ---------------- Attention layers 1&2: cross-batch pipeline at 6 waves/EU ------------------------
// r24 = r22's double-buffered schedule with __launch_bounds__(256, 6): the 8-deep pipeline
// needs ~48 VGPRs which spilled at the 64-VGPR/8-wave cap (r22: WRITE_SIZE 25->284 MB).
// Measured occupancy has been ~65% (~5.2 waves/SIMD) in every variant, so the nominal
// 8->6 cap costs nothing while the deeper pipeline doubles in-flight gather bytes.

__global__ __launch_bounds__(256, 6) void gat_attn8_r24(const uint4* __restrict__ h4,
                                                        const int* __restrict__ row_ptr,
                                                        const int* __restrict__ esrc,
                                                        const float* __restrict__ attn,
                                                        uint4* __restrict__ act4) {
    int t = threadIdx.x;
    int lane = t & 63, wv = t >> 6;
    int hf = lane >> 5, sub = lane & 31;
    int li = lane & 7;
    int n = blockIdx.x * 4 + wv;          // grid = NN/4 exactly
    float4 av0 = ((const float4*)attn)[sub * 2];
    float4 av1 = ((const float4*)attn)[sub * 2 + 1];
    f16x2 aw0 = {(_Float16)av0.x, (_Float16)av0.y};
    f16x2 aw1 = {(_Float16)av0.z, (_Float16)av0.w};
    f16x2 aw2 = {(_Float16)av1.x, (_Float16)av1.y};
    f16x2 aw3 = {(_Float16)av1.z, (_Float16)av1.w};
    const f16x2 c02 = {(_Float16)0.2f, (_Float16)0.2f};
    uint4 ud = h4[(long)n * 32 + sub];
    f16x2 hd0 = ash(ud.x), hd1 = ash(ud.y), hd2 = ash(ud.z), hd3 = ash(ud.w);
    int lo = __builtin_amdgcn_readfirstlane(row_ptr[n]);
    int hi = __builtin_amdgcn_readfirstlane(row_ptr[n + 1]);
    int clampv = hi - 1;                  // every node has >=1 in-edge
    float l = 0.f;
    f16x2 O0 = {}, O1 = {}, O2 = {}, O3 = {};
    int e = lo;
    int ia0 = lo + li;
    int myidx = esrc[ia0 < clampv ? ia0 : clampv];
    // prologue: issue batch-0 gathers
    uint4 u0 = {}, u1 = {}, u2 = {}, u3 = {};
    if (e + 8 <= hi) {
        int s0 = __shfl(myidx, 0 + hf, 8);
        int s1 = __shfl(myidx, 2 + hf, 8);
        int s2 = __shfl(myidx, 4 + hf, 8);
        int s3 = __shfl(myidx, 6 + hf, 8);
        u0 = h4[(long)s0 * 32 + sub];
        u1 = h4[(long)s1 * 32 + sub];
        u2 = h4[(long)s2 * 32 + sub];
        u3 = h4[(long)s3 * 32 + sub];
    }
    // ---- full batches of 8 edges, double-buffered ----
    for (; e + 8 <= hi; e += 8) {
        int ia = e + 8 + li;
        int nextidx = esrc[ia < clampv ? ia : clampv];
        // issue batch k+1 gathers before computing batch k
        uint4 n0 = {}, n1 = {}, n2 = {}, n3 = {};
        bool nextfull = (e + 16 <= hi);
        if (nextfull) {
            int s0 = __shfl(nextidx, 0 + hf, 8);
            int s1 = __shfl(nextidx, 2 + hf, 8);
            int s2 = __shfl(nextidx, 4 + hf, 8);
            int s3 = __shfl(nextidx, 6 + hf, 8);
            n0 = h4[(long)s0 * 32 + sub];
            n1 = h4[(long)s1 * 32 + sub];
            n2 = h4[(long)s2 * 32 + sub];
            n3 = h4[(long)s3 * 32 + sub];
        }
        // compute batch k
        #pragma unroll
        for (int j2 = 0; j2 < 4; ++j2) {
            uint4 u = (j2 == 0) ? u0 : (j2 == 1) ? u1 : (j2 == 2) ? u2 : u3;
            f16x2 x0 = ash(u.x), x1 = ash(u.y), x2 = ash(u.z), x3 = ash(u.w);
            f16x2 v0 = x0 + hd0, v1 = x1 + hd1, v2 = x2 + hd2, v3 = x3 + hd3;
            f16x2 r0 = __builtin_elementwise_max(v0, v0 * c02);
            f16x2 r1 = __builtin_elementwise_max(v1, v1 * c02);
            f16x2 r2 = __builtin_elementwise_max(v2, v2 * c02);
            f16x2 r3 = __builtin_elementwise_max(v3, v3 * c02);
            f16x2 acc = r0 * aw0;
            acc += r1 * aw1;
            acc += r2 * aw2;
            acc += r3 * aw3;
            float p = (float)acc.x + (float)acc.y;
            p += __shfl_xor(p, 1);
            p += __shfl_xor(p, 2);
            float w = __expf(p);
            l += w;
            _Float16 wh = (_Float16)w;
            f16x2 w2 = {wh, wh};
            O0 += x0 * w2; O1 += x1 * w2; O2 += x2 * w2; O3 += x3 * w2;
        }
        if (nextfull) { u0 = n0; u1 = n1; u2 = n2; u3 = n3; }
        myidx = nextidx;
    }
    // ---- tail 0..7 edges: validity-masked pairs ----
    for (int j = 0; e + j < hi; j += 2) {
        int srow = __shfl(myidx, j + hf, 8);
        uint4 u = h4[(long)srow * 32 + sub];
        f16x2 x0 = ash(u.x), x1 = ash(u.y), x2 = ash(u.z), x3 = ash(u.w);
        f16x2 v0 = x0 + hd0, v1 = x1 + hd1, v2 = x2 + hd2, v3 = x3 + hd3;
        f16x2 r0 = __builtin_elementwise_max(v0, v0 * c02);
        f16x2 r1 = __builtin_elementwise_max(v1, v1 * c02);
        f16x2 r2 = __builtin_elementwise_max(v2, v2 * c02);
        f16x2 r3 = __builtin_elementwise_max(v3, v3 * c02);
        f16x2 acc = r0 * aw0;
        acc += r1 * aw1;
        acc += r2 * aw2;
        acc += r3 * aw3;
        float p = (float)acc.x + (float)acc.y;
        p += __shfl_xor(p, 1);
        p += __shfl_xor(p, 2);
        float w = (e + j + hf < hi) ? __expf(p) : 0.f;
        l += w;
        _Float16 wh = (_Float16)w;
        f16x2 w2 = {wh, wh};
        O0 += x0 * w2; O1 += x1 * w2; O2 += x2 * w2; O3 += x3 * w2;
    }
    // merge halves
    l += __shfl_xor(l, 32);
    O0 += ash(__shfl_xor((int)h2u(O0), 32));
    O1 += ash(__shfl_xor((int)h2u(O1), 32));
    O2 += ash(__shfl_xor((int)h2u(O2), 32));
    O3 += ash(__shfl_xor((int)h2u(O3), 32));
    float rinv = 1.f / l;
    if (hf == 0) {
        uint4 outv;
        outv.x = pack2h(elu((float)O0.x * rinv), elu((float)O0.y * rinv));
        outv.y = pack2h(elu((float)O1.x * rinv), elu((float)O1.y * rinv));
        outv.z = pack2h(elu((float)O2.x * rinv), elu((float)O2.y * rinv));
        outv.w = pack2h(elu((float)O3.x * rinv), elu((float)O3.y * rinv));
        act4[(long)n * 32 + sub] = outv;
    }
}

// ---------------- Attention layer 3: quarter-wave, double-buffered row gathers + max-pool ----------

__global__ __launch_bounds__(256) void gat_attn1_r24(const uint2* __restrict__ h2,
                                                     const int* __restrict__ row_ptr,
                                                     const int* __restrict__ esrc,
                                                     const float* __restrict__ attn,
                                                     float* __restrict__ blockmax) {
    int t = threadIdx.x;
    int lane = t & 63, wv = t >> 6;
    int g = lane >> 4, sub = lane & 15;
    float4 aq = ((const float4*)attn)[sub];
    f16x2 aw0 = {(_Float16)aq.x, (_Float16)aq.y};
    f16x2 aw1 = {(_Float16)aq.z, (_Float16)aq.w};
    const f16x2 c02 = {(_Float16)0.2f, (_Float16)0.2f};
    float b0 = -1e30f, b1 = -1e30f, b2 = -1e30f, b3 = -1e30f;
    for (int n = blockIdx.x * 4 + wv; n < NN; n += gridDim.x * 4) {
        uint2 ud = h2[(long)n * 16 + sub];
        f16x2 hd0 = ash(ud.x), hd1 = ash(ud.y);
        int lo = row_ptr[n], hi = row_ptr[n + 1];
        float l = 0.f;
        f16x2 O0 = {}, O1 = {};
        int eg = lo + g;
        int s = esrc[(eg < hi) ? eg : hi - 1];
        uint2 ucur = h2[(long)s * 16 + sub];             // iter-0 row in flight
        for (int e = lo; e < hi; e += 4) {
            int egn = e + 4 + g;
            int snext = esrc[(egn < hi) ? egn : hi - 1];
            bool more = (e + 4 < hi);
            uint2 unext = {};
            if (more) unext = h2[(long)snext * 16 + sub]; // next-iter row issued before compute
            bool valid = e + g < hi;
            f16x2 x0 = ash(ucur.x), x1 = ash(ucur.y);
            f16x2 v0 = x0 + hd0, v1 = x1 + hd1;
            f16x2 r0 = __builtin_elementwise_max(v0, v0 * c02);
            f16x2 r1 = __builtin_elementwise_max(v1, v1 * c02);
            f16x2 acc = r0 * aw0;
            acc += r1 * aw1;
            float p = (float)acc.x + (float)acc.y;
            p += __shfl_xor(p, 1);
            p += __shfl_xor(p, 2);
            p += __shfl_xor(p, 4);
            p += __shfl_xor(p, 8);
            float w = valid ? __expf(p) : 0.f;
            l += w;
            _Float16 wh = (_Float16)w;
            f16x2 w2 = {wh, wh};
            O0 += x0 * w2;
            O1 += x1 * w2;
            if (more) ucur = unext;
        }
        l += __shfl_xor(l, 16); l += __shfl_xor(l, 32);
        O0 += ash(__shfl_xor((int)h2u(O0), 16));
        O0 += ash(__shfl_xor((int)h2u(O0), 32));
        O1 += ash(__shfl_xor((int)h2u(O1), 16));
        O1 += ash(__shfl_xor((int)h2u(O1), 32));
        float rinv = 1.f / l;
        b0 = fmaxf(b0, (float)O0.x * rinv); b1 = fmaxf(b1, (float)O0.y * rinv);
        b2 = fmaxf(b2, (float)O1.x * rinv); b3 = fmaxf(b3, (float)O1.y * rinv);
    }
    __shared__ float4 sm4[4][16];
    if (lane < 16) { float4 v; v.x = b0; v.y = b1; v.z = b2; v.w = b3; sm4[wv][sub] = v; }
    __syncthreads();
    if (wv == 0 && lane < 16) {
        float4 r = sm4[0][sub];
        #pragma unroll
        for (int i = 1; i < 4; ++i) {
            float4 q = sm4[i][sub];
            r.x = fmaxf(r.x, q.x); r.y = fmaxf(r.y, q.y);
            r.z = fmaxf(r.z, q.z); r.w = fmaxf(r.w, q.w);
        }
        ((float4*)(blockmax + (long)blockIdx.x * 64))[sub] = r;
    }
}

__global__ __launch_bounds__(1024) void gat_final_r24(const float* __restrict__ blockmax,
                                                      float* __restrict__ out) {
    __shared__ float sm[16][64];
    int t = threadIdx.x;
    int lane = t & 63, wv = t >> 6;
    float v = -1e30f;
    for (int b = wv; b < A1_BLOCKS; b += 16)
        v = fmaxf(v, blockmax[(long)b * 64 + lane]);
    sm[wv][lane] = v;
    __syncthreads();
    if (wv == 0) {
        float r = sm[0][lane];
        #pragma unroll
        for (int i = 1; i < 16; ++i) r = fmaxf(r, sm[i][lane]);
        out[lane] = r;
    }
}

// ---------------- launch ----------------

extern "C" void kernel_launch(void* const* d_in, const int* in_sizes, int n_in,
                              void* d_out, int out_size, void* d_ws, size_t ws_size,
                              hipStream_t stream) {
    const float* x     = (const float*)d_in[0];
    const int*   src   = (const int*)  d_in[1];
    const int*   dst   = (const int*)  d_in[2];
    const float* W1    = (const float*)d_in[3];
    const float* b1    = (const float*)d_in[4];
    const float* attn1 = (const float*)d_in[5];
    const float* W2    = (const float*)d_in[6];
    const float* b2    = (const float*)d_in[7];
    const float* attn2 = (const float*)d_in[8];
    const float* W3    = (const float*)d_in[9];
    const float* b3    = (const float*)d_in[10];
    const float* attn3 = (const float*)d_in[11];
    float* out = (float*)d_out;

    char* ws = (char*)d_ws;
    size_t off = 0;
    auto carve = [&](size_t bytes) { void* p = ws + off; off += (bytes + 255) & ~size_t(255); return p; };
    u16*   P        = (u16*)  carve((size_t)NN * 256 * 2);
    u16*   Q        = (u16*)  carve((size_t)NN * 256 * 2);
    u16*   h3       = (u16*)  carve((size_t)NN * 64 * 2);
    int*   row_ptr  = (int*)  carve((size_t)(NN + 1) * 4);
    int*   deg      = (int*)  carve((size_t)NN * 4);
    int*   cursor   = (int*)  carve((size_t)NN * 4);
    int*   esrc     = (int*)  carve((size_t)EE * 4);
    float* blockmax = (float*)carve((size_t)A1_BLOCKS * 64 * 4);
    int*   bsum     = (int*)  carve((size_t)SCAN_B * 4);
    u16*   W1t      = (u16*)  carve((size_t)256 * 128 * 2);
    u16*   W2t      = (u16*)  carve((size_t)256 * 256 * 2);
    u16*   W3t      = (u16*)  carve((size_t)64 * 256 * 2);

    gat_prep_r24<<<576 + SCAN_B, 256, 0, stream>>>(W1, W2, W3, W1t, W2t, W3t, deg);
    gat_fuse1_r24<<<G1_TILES + CNT_B, 256, 0, stream>>>(x, W1t, b1, P, dst, deg);
    gat_scana_r24<<<SCAN_B, 256, 0, stream>>>(deg, bsum);
    gat_scanc_r24<<<SCAN_B, 256, 0, stream>>>(deg, bsum, row_ptr, cursor);
    gat_scatter_r24<<<CNT_B, 256, 0, stream>>>(src, dst, cursor, esrc);

    gat_attn8_r24<<<NN / 4, 256, 0, stream>>>((const uint4*)P, row_ptr, esrc, attn1, (uint4*)Q);

    gat_gemm2_r24<<<(NN + 63) / 64, 256, 0, stream>>>(Q, W2t, b2, P);
    gat_attn8_r24<<<NN / 4, 256, 0, stream>>>((const uint4*)P, row_ptr, esrc, attn2, (uint4*)Q);

    gat_gemm64_r24<<<dim3((NN + 63) / 64, 1), 256, 0, stream>>>(Q, W3t, b3, h3, NN, 256, 64);
    gat_attn1_r24<<<A1_BLOCKS, 256, 0, stream>>>((const uint2*)h3, row_ptr, esrc, attn3, blockmax);

    gat_final_r24<<<1, 1024, 0, stream>>>(blockmax, out);
}

// Round 8
// 403.519 us; speedup vs baseline: 1.0352x; 1.0352x over previous
//
#include <hip/hip_runtime.h>
#include <hip/hip_bf16.h>

typedef unsigned int u32;
typedef unsigned short u16;
typedef _Float16 f16x2 __attribute__((ext_vector_type(2)));
typedef _Float16 f16x8 __attribute__((ext_vector_type(8)));
typedef float f32x4 __attribute__((ext_vector_type(4)));

#define NN 50000
#define EE 800000
#define A1_BLOCKS 4096
#define SCAN_B ((NN + 255) / 256)     // 196
#define G1_TILES (((NN + 63) / 64) * 2)   // 1564 gemm1 blocks (BN=128, Nc=256)
#define CNT_B ((EE + 255) / 256)      // 3125 count blocks

__device__ __forceinline__ f16x2 ash(u32 u) { union { u32 u; f16x2 h; } c; c.u = u; return c.h; }
__device__ __forceinline__ u32 h2u(f16x2 h) { union { u32 u; f16x2 h; } c; c.h = h; return c.u; }
__device__ __forceinline__ u16 f2h(float v) { _Float16 h = (_Float16)v; return *(u16*)&h; }
__device__ __forceinline__ u32 pack2h(float a, float b) {
    return (u32)f2h(a) | ((u32)f2h(b) << 16);
}
__device__ __forceinline__ float elu(float v) { return v > 0.f ? v : __expf(v) - 1.f; }

// ---------------- prep: weight transpose->f16 (blocks 0-575) + deg zero (blocks 576+) ----------------

__global__ __launch_bounds__(256) void gat_prep_r25(const float* __restrict__ W1,
                                                    const float* __restrict__ W2,
                                                    const float* __restrict__ W3,
                                                    u16* __restrict__ W1t,
                                                    u16* __restrict__ W2t,
                                                    u16* __restrict__ W3t,
                                                    int* __restrict__ deg) {
    int b = blockIdx.x, t = threadIdx.x;
    if (b < 256) {
        if (t < 128) W1t[(long)b * 128 + t] = f2h(W1[(long)t * 256 + b]);
    } else if (b < 512) {
        int n = b - 256;
        W2t[(long)n * 256 + t] = f2h(W2[(long)t * 256 + n]);
    } else if (b < 576) {
        int n = b - 512;
        W3t[(long)n * 256 + t] = f2h(W3[(long)t * 64 + n]);
    } else {
        int i = (b - 576) * 256 + t;
        if (i < NN) deg[i] = 0;
    }
}

// ---------------- MFMA GEMM BN=128 body (layer-1 fused kernel) ----------------

template <int AHF>
__device__ __forceinline__ void gemm128_body(const void* __restrict__ Ain,
                                             const u16* __restrict__ Wt,
                                             const float* __restrict__ bias,
                                             u16* __restrict__ C,
                                             int M, int K, int Nc,
                                             int bm, int bn) {
    __shared__ __align__(16) u16 As[64 * 40];
    __shared__ __align__(16) u16 Bs[128 * 40];
    const int t    = threadIdx.x;
    const int w    = t >> 6;
    const int lane = t & 63;
    const int sm   = t >> 2;
    const int sk   = (t & 3) * 8;
    const int fq   = (lane >> 4) * 8;
    const int fr   = lane & 15;
    const int nbase = w * 32;

    f32x4 acc[4][2] = {};

    for (int k0 = 0; k0 < K; k0 += 32) {
        {
            int gr = bm + sm;
            f16x8 av = {};
            if (gr < M) {
                if (AHF) {
                    av = *(const f16x8*)((const u16*)Ain + (long)gr * K + k0 + sk);
                } else {
                    const float* p = (const float*)Ain + (long)gr * K + k0 + sk;
                    #pragma unroll
                    for (int i = 0; i < 8; ++i) av[i] = (_Float16)p[i];
                }
            }
            *(f16x8*)&As[sm * 40 + sk] = av;
        }
        #pragma unroll
        for (int i = 0; i < 2; ++i) {
            int tau = t + i * 256;
            int row = tau >> 2, ck = (tau & 3) * 8;
            f16x8 bv = *(const f16x8*)(Wt + (long)(bn + row) * K + k0 + ck);
            *(f16x8*)&Bs[row * 40 + ck] = bv;
        }
        __syncthreads();
        f16x8 afr[4], bfr[2];
        #pragma unroll
        for (int mt = 0; mt < 4; ++mt)
            afr[mt] = *(const f16x8*)&As[(mt * 16 + fr) * 40 + fq];
        #pragma unroll
        for (int nt = 0; nt < 2; ++nt)
            bfr[nt] = *(const f16x8*)&Bs[(nbase + nt * 16 + fr) * 40 + fq];
        #pragma unroll
        for (int mt = 0; mt < 4; ++mt)
            #pragma unroll
            for (int nt = 0; nt < 2; ++nt)
                acc[mt][nt] = __builtin_amdgcn_mfma_f32_16x16x32_f16(
                    afr[mt], bfr[nt], acc[mt][nt], 0, 0, 0);
        __syncthreads();
    }
    #pragma unroll
    for (int mt = 0; mt < 4; ++mt) {
        #pragma unroll
        for (int r = 0; r < 4; ++r) {
            int row = bm + mt * 16 + (lane >> 4) * 4 + r;
            if (row >= M) continue;
            #pragma unroll
            for (int nt = 0; nt < 2; ++nt) {
                int col = bn + nbase + nt * 16 + fr;
                C[(long)row * Nc + col] = f2h(acc[mt][nt][r] + bias[col]);
            }
        }
    }
}

// ---------------- fused: layer-1 GEMM + degree count (independent, concurrent) ----------------

__global__ __launch_bounds__(256) void gat_fuse1_r25(const float* __restrict__ x,
                                                     const u16* __restrict__ W1t,
                                                     const float* __restrict__ b1,
                                                     u16* __restrict__ P,
                                                     const int* __restrict__ dst,
                                                     int* __restrict__ deg) {
    int b = blockIdx.x;
    if (b < G1_TILES) {
        int bm = (b >> 1) * 64;
        int bn = (b & 1) * 128;
        gemm128_body<0>(x, W1t, b1, P, NN, 128, 256, bm, bn);
    } else {
        int e = (b - G1_TILES) * 256 + threadIdx.x;
        if (e < EE) atomicAdd(&deg[dst[e]], 1);
    }
}

// ---------------- layer-2 GEMM: BM=64 x BN=256 single pass (A read once; neutral-to-better) -------

__global__ __launch_bounds__(256) void gat_gemm2_r25(const u16* __restrict__ Q,
                                                     const u16* __restrict__ W2t,
                                                     const float* __restrict__ b2,
                                                     u16* __restrict__ P) {
    __shared__ __align__(16) u16 As[64 * 40];
    __shared__ __align__(16) u16 Bs[256 * 40];
    const int t    = threadIdx.x;
    const int w    = t >> 6;
    const int lane = t & 63;
    const int sm   = t >> 2;
    const int sk   = (t & 3) * 8;
    const int fq   = (lane >> 4) * 8;
    const int fr   = lane & 15;
    const int nbase = w * 64;
    const int bm   = blockIdx.x * 64;

    f32x4 acc[4][4] = {};

    for (int k0 = 0; k0 < 256; k0 += 32) {
        {
            int gr = bm + sm;
            f16x8 av = {};
            if (gr < NN) av = *(const f16x8*)(Q + (long)gr * 256 + k0 + sk);
            *(f16x8*)&As[sm * 40 + sk] = av;
        }
        #pragma unroll
        for (int i = 0; i < 4; ++i) {
            int tau = t + i * 256;
            int row = tau >> 2, ck = (tau & 3) * 8;
            f16x8 bv = *(const f16x8*)(W2t + (long)row * 256 + k0 + ck);
            *(f16x8*)&Bs[row * 40 + ck] = bv;
        }
        __syncthreads();
        f16x8 afr[4], bfr[4];
        #pragma unroll
        for (int mt = 0; mt < 4; ++mt)
            afr[mt] = *(const f16x8*)&As[(mt * 16 + fr) * 40 + fq];
        #pragma unroll
        for (int nt = 0; nt < 4; ++nt)
            bfr[nt] = *(const f16x8*)&Bs[(nbase + nt * 16 + fr) * 40 + fq];
        #pragma unroll
        for (int mt = 0; mt < 4; ++mt)
            #pragma unroll
            for (int nt = 0; nt < 4; ++nt)
                acc[mt][nt] = __builtin_amdgcn_mfma_f32_16x16x32_f16(
                    afr[mt], bfr[nt], acc[mt][nt], 0, 0, 0);
        __syncthreads();
    }
    #pragma unroll
    for (int mt = 0; mt < 4; ++mt) {
        #pragma unroll
        for (int r = 0; r < 4; ++r) {
            int row = bm + mt * 16 + (lane >> 4) * 4 + r;
            if (row >= NN) continue;
            #pragma unroll
            for (int nt = 0; nt < 4; ++nt) {
                int col = nbase + nt * 16 + fr;
                P[(long)row * 256 + col] = f2h(acc[mt][nt][r] + b2[col]);
            }
        }
    }
}

// ---------------- CSR scan + scatter ----------------

__global__ __launch_bounds__(256) void gat_scana_r25(const int* __restrict__ deg,
                                                     int* __restrict__ bsum) {
    __shared__ int s[256];
    int t = threadIdx.x;
    int i = blockIdx.x * 256 + t;
    s[t] = (i < NN) ? deg[i] : 0;
    __syncthreads();
    for (int o = 128; o > 0; o >>= 1) {
        if (t < o) s[t] += s[t + o];
        __syncthreads();
    }
    if (t == 0) bsum[blockIdx.x] = s[0];
}

__global__ __launch_bounds__(256) void gat_scanc_r25(const int* __restrict__ deg,
                                                     const int* __restrict__ bsum,
                                                     int* __restrict__ row_ptr,
                                                     int* __restrict__ cursor) {
    __shared__ int sb[256];
    __shared__ int s[256];
    int t = threadIdx.x;
    sb[t] = (t < SCAN_B) ? bsum[t] : 0;
    __syncthreads();
    for (int o = 1; o < 256; o <<= 1) {
        int u = (t >= o) ? sb[t - o] : 0;
        __syncthreads();
        sb[t] += u;
        __syncthreads();
    }
    int boff = (blockIdx.x == 0) ? 0 : sb[blockIdx.x - 1];
    if (blockIdx.x == 0 && t == 0) row_ptr[NN] = sb[SCAN_B - 1];
    int i = blockIdx.x * 256 + t;
    int v = (i < NN) ? deg[i] : 0;
    s[t] = v;
    __syncthreads();
    for (int o = 1; o < 256; o <<= 1) {
        int u = (t >= o) ? s[t - o] : 0;
        __syncthreads();
        s[t] += u;
        __syncthreads();
    }
    if (i < NN) {
        int excl = s[t] - v + boff;
        row_ptr[i] = excl;
        cursor[i]  = excl;
    }
}

__global__ void gat_scatter_r25(const int* __restrict__ src, const int* __restrict__ dst,
                                int* __restrict__ cursor, int* __restrict__ esrc) {
    int e = blockIdx.x * 256 + threadIdx.x;
    if (e < EE) {
        int pos = atomicAdd(&cursor[dst[e]], 1);
        esrc[pos] = src[e];
    }
}

// ---------------- MFMA GEMM, BN=64 — layer 3 (Nc=64) ----------------

__global__ __launch_bounds__(256) void gat_gemm64_r25(const u16* __restrict__ Ain,
                                                      const u16* __restrict__ Wt,
                                                      const float* __restrict__ bias,
                                                      u16* __restrict__ C,
                                                      int M, int K, int Nc) {
    __shared__ __align__(16) u16 As[64 * 40];
    __shared__ __align__(16) u16 Bs[64 * 40];
    const int t    = threadIdx.x;
    const int bm   = blockIdx.x * 64;
    const int bn   = blockIdx.y * 64;
    const int w    = t >> 6;
    const int lane = t & 63;
    const int sm   = t >> 2;
    const int sk   = (t & 3) * 8;
    const int mbase = (w & 1) * 32;
    const int nbase = (w >> 1) * 32;
    const int fq    = (lane >> 4) * 8;
    const int fr    = lane & 15;

    f32x4 acc[2][2] = {};

    for (int k0 = 0; k0 < K; k0 += 32) {
        {
            int gr = bm + sm;
            f16x8 av = {};
            if (gr < M) av = *(const f16x8*)(Ain + (long)gr * K + k0 + sk);
            *(f16x8*)&As[sm * 40 + sk] = av;
        }
        {
            f16x8 bv = *(const f16x8*)(Wt + (long)(bn + sm) * K + k0 + sk);
            *(f16x8*)&Bs[sm * 40 + sk] = bv;
        }
        __syncthreads();
        f16x8 afr[2], bfr[2];
        #pragma unroll
        for (int mt = 0; mt < 2; ++mt)
            afr[mt] = *(const f16x8*)&As[(mbase + mt * 16 + fr) * 40 + fq];
        #pragma unroll
        for (int nt = 0; nt < 2; ++nt)
            bfr[nt] = *(const f16x8*)&Bs[(nbase + nt * 16 + fr) * 40 + fq];
        #pragma unroll
        for (int mt = 0; mt < 2; ++mt)
            #pragma unroll
            for (int nt = 0; nt < 2; ++nt)
                acc[mt][nt] = __builtin_amdgcn_mfma_f32_16x16x32_f16(
                    afr[mt], bfr[nt], acc[mt][nt], 0, 0, 0);
        __syncthreads();
    }
    #pragma unroll
    for (int mt = 0; mt < 2; ++mt) {
        #pragma unroll
        for (int r = 0; r < 4; ++r) {
            int row = bm + mbase + mt * 16 + (lane >> 4) * 4 + r;
            if (row >= M) continue;
            #pragma unroll
            for (int nt = 0; nt < 2; ++nt) {
                int col = bn + nbase + nt * 16 + fr;
                C[(long)row * Nc + col] = f2h(acc[mt][nt][r] + bias[col]);
            }
        }
    }
}

// ---------------- Attention layers 1&2: half-wave pairing, phase-split gathers (r23-exact) ---------
// Banked optimum for this kernel: cross-batch pipelining refuted 3x (spill @8w, occupancy @6w).

__global__ __launch_bounds__(256, 8) void gat_attn8_r25(const uint4* __restrict__ h4,
                                                        const int* __restrict__ row_ptr,
                                                        const int* __restrict__ esrc,
                                                        const float* __restrict__ attn,
                                                        uint4* __restrict__ act4) {
    int t = threadIdx.x;
    int lane = t & 63, wv = t >> 6;
    int hf = lane >> 5, sub = lane & 31;
    int li = lane & 7;
    int n = blockIdx.x * 4 + wv;          // grid = NN/4 exactly
    float4 av0 = ((const float4*)attn)[sub * 2];
    float4 av1 = ((const float4*)attn)[sub * 2 + 1];
    f16x2 aw0 = {(_Float16)av0.x, (_Float16)av0.y};
    f16x2 aw1 = {(_Float16)av0.z, (_Float16)av0.w};
    f16x2 aw2 = {(_Float16)av1.x, (_Float16)av1.y};
    f16x2 aw3 = {(_Float16)av1.z, (_Float16)av1.w};
    const f16x2 c02 = {(_Float16)0.2f, (_Float16)0.2f};
    uint4 ud = h4[(long)n * 32 + sub];
    f16x2 hd0 = ash(ud.x), hd1 = ash(ud.y), hd2 = ash(ud.z), hd3 = ash(ud.w);
    int lo = __builtin_amdgcn_readfirstlane(row_ptr[n]);
    int hi = __builtin_amdgcn_readfirstlane(row_ptr[n + 1]);
    int clampv = hi - 1;                  // every node has >=1 in-edge
    float l = 0.f;
    f16x2 O0 = {}, O1 = {}, O2 = {}, O3 = {};
    int e = lo;
    int ia0 = lo + li;
    int myidx = esrc[ia0 < clampv ? ia0 : clampv];
    // ---- full batches of 8 edges ----
    for (; e + 8 <= hi; e += 8) {
        int ia = e + 8 + li;
        int nextidx = esrc[ia < clampv ? ia : clampv];
        // phase 1: all four source rows (independent shfls)
        int srow[4];
        #pragma unroll
        for (int j2 = 0; j2 < 4; ++j2) srow[j2] = __shfl(myidx, 2 * j2 + hf, 8);
        // phase 2: all four gathers in flight
        uint4 u[4];
        #pragma unroll
        for (int j2 = 0; j2 < 4; ++j2) u[j2] = h4[(long)srow[j2] * 32 + sub];
        // phase 3: compute
        #pragma unroll
        for (int j2 = 0; j2 < 4; ++j2) {
            f16x2 x0 = ash(u[j2].x), x1 = ash(u[j2].y), x2 = ash(u[j2].z), x3 = ash(u[j2].w);
            f16x2 v0 = x0 + hd0, v1 = x1 + hd1, v2 = x2 + hd2, v3 = x3 + hd3;
            f16x2 r0 = __builtin_elementwise_max(v0, v0 * c02);
            f16x2 r1 = __builtin_elementwise_max(v1, v1 * c02);
            f16x2 r2 = __builtin_elementwise_max(v2, v2 * c02);
            f16x2 r3 = __builtin_elementwise_max(v3, v3 * c02);
            f16x2 acc = r0 * aw0;
            acc += r1 * aw1;
            acc += r2 * aw2;
            acc += r3 * aw3;
            float p = (float)acc.x + (float)acc.y;
            p += __shfl_xor(p, 1);
            p += __shfl_xor(p, 2);
            float w = __expf(p);
            l += w;
            _Float16 wh = (_Float16)w;
            f16x2 w2 = {wh, wh};
            O0 += x0 * w2; O1 += x1 * w2; O2 += x2 * w2; O3 += x3 * w2;
        }
        myidx = nextidx;
    }
    // ---- tail 0..7 edges: validity-masked pairs ----
    for (int j = 0; e + j < hi; j += 2) {
        int srow = __shfl(myidx, j + hf, 8);
        uint4 u = h4[(long)srow * 32 + sub];
        f16x2 x0 = ash(u.x), x1 = ash(u.y), x2 = ash(u.z), x3 = ash(u.w);
        f16x2 v0 = x0 + hd0, v1 = x1 + hd1, v2 = x2 + hd2, v3 = x3 + hd3;
        f16x2 r0 = __builtin_elementwise_max(v0, v0 * c02);
        f16x2 r1 = __builtin_elementwise_max(v1, v1 * c02);
        f16x2 r2 = __builtin_elementwise_max(v2, v2 * c02);
        f16x2 r3 = __builtin_elementwise_max(v3, v3 * c02);
        f16x2 acc = r0 * aw0;
        acc += r1 * aw1;
        acc += r2 * aw2;
        acc += r3 * aw3;
        float p = (float)acc.x + (float)acc.y;
        p += __shfl_xor(p, 1);
        p += __shfl_xor(p, 2);
        float w = (e + j + hf < hi) ? __expf(p) : 0.f;
        l += w;
        _Float16 wh = (_Float16)w;
        f16x2 w2 = {wh, wh};
        O0 += x0 * w2; O1 += x1 * w2; O2 += x2 * w2; O3 += x3 * w2;
    }
    // merge halves
    l += __shfl_xor(l, 32);
    O0 += ash(__shfl_xor((int)h2u(O0), 32));
    O1 += ash(__shfl_xor((int)h2u(O1), 32));
    O2 += ash(__shfl_xor((int)h2u(O2), 32));
    O3 += ash(__shfl_xor((int)h2u(O3), 32));
    float rinv = 1.f / l;
    if (hf == 0) {
        uint4 outv;
        outv.x = pack2h(elu((float)O0.x * rinv), elu((float)O0.y * rinv));
        outv.y = pack2h(elu((float)O1.x * rinv), elu((float)O1.y * rinv));
        outv.z = pack2h(elu((float)O2.x * rinv), elu((float)O2.y * rinv));
        outv.w = pack2h(elu((float)O3.x * rinv), elu((float)O3.y * rinv));
        act4[(long)n * 32 + sub] = outv;
    }
}

// ---------------- Attention layer 3: 8-lane groups, 8 edges/step, uint4 rows + max-pool ------------
// r25: was 16-lane groups (4 edges/step, 4 shfl levels); now 8-lane groups x uint4 (16B/lane):
// 8 edges/step, 3 shfl levels, ~2 steps/node -> roughly halves the serial gather+shfl chain.

__global__ __launch_bounds__(256) void gat_attn1_r25(const uint4* __restrict__ h4,
                                                     const int* __restrict__ row_ptr,
                                                     const int* __restrict__ esrc,
                                                     const float* __restrict__ attn,
                                                     float* __restrict__ blockmax) {
    int t = threadIdx.x;
    int lane = t & 63, wv = t >> 6;
    int g = lane >> 3, sub = lane & 7;    // 8 groups of 8 lanes; lane sub holds cols 8*sub..8*sub+7
    float4 aq0 = ((const float4*)attn)[sub * 2];
    float4 aq1 = ((const float4*)attn)[sub * 2 + 1];
    f16x2 aw0 = {(_Float16)aq0.x, (_Float16)aq0.y};
    f16x2 aw1 = {(_Float16)aq0.z, (_Float16)aq0.w};
    f16x2 aw2 = {(_Float16)aq1.x, (_Float16)aq1.y};
    f16x2 aw3 = {(_Float16)aq1.z, (_Float16)aq1.w};
    const f16x2 c02 = {(_Float16)0.2f, (_Float16)0.2f};
    float b0 = -1e30f, b1 = -1e30f, b2 = -1e30f, b3 = -1e30f;
    float b4 = -1e30f, b5 = -1e30f, b6 = -1e30f, b7 = -1e30f;
    for (int n = blockIdx.x * 4 + wv; n < NN; n += gridDim.x * 4) {
        uint4 ud = h4[(long)n * 8 + sub];
        f16x2 hd0 = ash(ud.x), hd1 = ash(ud.y), hd2 = ash(ud.z), hd3 = ash(ud.w);
        int lo = row_ptr[n], hi = row_ptr[n + 1];
        float l = 0.f;
        f16x2 O0 = {}, O1 = {}, O2 = {}, O3 = {};
        int eg = lo + g;
        int s = esrc[(eg < hi) ? eg : hi - 1];
        uint4 ucur = h4[(long)s * 8 + sub];              // iter-0 row in flight
        for (int e = lo; e < hi; e += 8) {
            int egn = e + 8 + g;
            int snext = esrc[(egn < hi) ? egn : hi - 1];
            bool more = (e + 8 < hi);
            uint4 unext = {};
            if (more) unext = h4[(long)snext * 8 + sub]; // next-iter row issued before compute
            bool valid = e + g < hi;
            f16x2 x0 = ash(ucur.x), x1 = ash(ucur.y), x2 = ash(ucur.z), x3 = ash(ucur.w);
            f16x2 v0 = x0 + hd0, v1 = x1 + hd1, v2 = x2 + hd2, v3 = x3 + hd3;
            f16x2 r0 = __builtin_elementwise_max(v0, v0 * c02);
            f16x2 r1 = __builtin_elementwise_max(v1, v1 * c02);
            f16x2 r2 = __builtin_elementwise_max(v2, v2 * c02);
            f16x2 r3 = __builtin_elementwise_max(v3, v3 * c02);
            f16x2 acc = r0 * aw0;
            acc += r1 * aw1;
            acc += r2 * aw2;
            acc += r3 * aw3;
            float p = (float)acc.x + (float)acc.y;
            p += __shfl_xor(p, 1);
            p += __shfl_xor(p, 2);
            p += __shfl_xor(p, 4);
            float w = valid ? __expf(p) : 0.f;
            l += w;
            _Float16 wh = (_Float16)w;
            f16x2 w2 = {wh, wh};
            O0 += x0 * w2; O1 += x1 * w2; O2 += x2 * w2; O3 += x3 * w2;
            if (more) ucur = unext;
        }
        // merge 8 groups (levels 8,16,32)
        l += __shfl_xor(l, 8); l += __shfl_xor(l, 16); l += __shfl_xor(l, 32);
        O0 += ash(__shfl_xor((int)h2u(O0), 8));
        O0 += ash(__shfl_xor((int)h2u(O0), 16));
        O0 += ash(__shfl_xor((int)h2u(O0), 32));
        O1 += ash(__shfl_xor((int)h2u(O1), 8));
        O1 += ash(__shfl_xor((int)h2u(O1), 16));
        O1 += ash(__shfl_xor((int)h2u(O1), 32));
        O2 += ash(__shfl_xor((int)h2u(O2), 8));
        O2 += ash(__shfl_xor((int)h2u(O2), 16));
        O2 += ash(__shfl_xor((int)h2u(O2), 32));
        O3 += ash(__shfl_xor((int)h2u(O3), 8));
        O3 += ash(__shfl_xor((int)h2u(O3), 16));
        O3 += ash(__shfl_xor((int)h2u(O3), 32));
        float rinv = 1.f / l;
        b0 = fmaxf(b0, (float)O0.x * rinv); b1 = fmaxf(b1, (float)O0.y * rinv);
        b2 = fmaxf(b2, (float)O1.x * rinv); b3 = fmaxf(b3, (float)O1.y * rinv);
        b4 = fmaxf(b4, (float)O2.x * rinv); b5 = fmaxf(b5, (float)O2.y * rinv);
        b6 = fmaxf(b6, (float)O3.x * rinv); b7 = fmaxf(b7, (float)O3.y * rinv);
    }
    __shared__ float sm[4][64];
    if (g == 0) {
        sm[wv][sub * 8 + 0] = b0; sm[wv][sub * 8 + 1] = b1;
        sm[wv][sub * 8 + 2] = b2; sm[wv][sub * 8 + 3] = b3;
        sm[wv][sub * 8 + 4] = b4; sm[wv][sub * 8 + 5] = b5;
        sm[wv][sub * 8 + 6] = b6; sm[wv][sub * 8 + 7] = b7;
    }
    __syncthreads();
    if (wv == 0) {
        float r = sm[0][lane];
        #pragma unroll
        for (int i = 1; i < 4; ++i) r = fmaxf(r, sm[i][lane]);
        blockmax[(long)blockIdx.x * 64 + lane] = r;
    }
}

__global__ __launch_bounds__(1024) void gat_final_r25(const float* __restrict__ blockmax,
                                                      float* __restrict__ out) {
    __shared__ float sm[16][64];
    int t = threadIdx.x;
    int lane = t & 63, wv = t >> 6;
    float v = -1e30f;
    for (int b = wv; b < A1_BLOCKS; b += 16)
        v = fmaxf(v, blockmax[(long)b * 64 + lane]);
    sm[wv][lane] = v;
    __syncthreads();
    if (wv == 0) {
        float r = sm[0][lane];
        #pragma unroll
        for (int i = 1; i < 16; ++i) r = fmaxf(r, sm[i][lane]);
        out[lane] = r;
    }
}

// ---------------- launch ----------------

extern "C" void kernel_launch(void* const* d_in, const int* in_sizes, int n_in,
                              void* d_out, int out_size, void* d_ws, size_t ws_size,
                              hipStream_t stream) {
    const float* x     = (const float*)d_in[0];
    const int*   src   = (const int*)  d_in[1];
    const int*   dst   = (const int*)  d_in[2];
    const float* W1    = (const float*)d_in[3];
    const float* b1    = (const float*)d_in[4];
    const float* attn1 = (const float*)d_in[5];
    const float* W2    = (const float*)d_in[6];
    const float* b2    = (const float*)d_in[7];
    const float* attn2 = (const float*)d_in[8];
    const float* W3    = (const float*)d_in[9];
    const float* b3    = (const float*)d_in[10];
    const float* attn3 = (const float*)d_in[11];
    float* out = (float*)d_out;

    char* ws = (char*)d_ws;
    size_t off = 0;
    auto carve = [&](size_t bytes) { void* p = ws + off; off += (bytes + 255) & ~size_t(255); return p; };
    u16*   P        = (u16*)  carve((size_t)NN * 256 * 2);
    u16*   Q        = (u16*)  carve((size_t)NN * 256 * 2);
    u16*   h3       = (u16*)  carve((size_t)NN * 64 * 2);
    int*   row_ptr  = (int*)  carve((size_t)(NN + 1) * 4);
    int*   deg      = (int*)  carve((size_t)NN * 4);
    int*   cursor   = (int*)  carve((size_t)NN * 4);
    int*   esrc     = (int*)  carve((size_t)EE * 4);
    float* blockmax = (float*)carve((size_t)A1_BLOCKS * 64 * 4);
    int*   bsum     = (int*)  carve((size_t)SCAN_B * 4);
    u16*   W1t      = (u16*)  carve((size_t)256 * 128 * 2);
    u16*   W2t      = (u16*)  carve((size_t)256 * 256 * 2);
    u16*   W3t      = (u16*)  carve((size_t)64 * 256 * 2);

    gat_prep_r25<<<576 + SCAN_B, 256, 0, stream>>>(W1, W2, W3, W1t, W2t, W3t, deg);
    gat_fuse1_r25<<<G1_TILES + CNT_B, 256, 0, stream>>>(x, W1t, b1, P, dst, deg);
    gat_scana_r25<<<SCAN_B, 256, 0, stream>>>(deg, bsum);
    gat_scanc_r25<<<SCAN_B, 256, 0, stream>>>(deg, bsum, row_ptr, cursor);
    gat_scatter_r25<<<CNT_B, 256, 0, stream>>>(src, dst, cursor, esrc);

    gat_attn8_r25<<<NN / 4, 256, 0, stream>>>((const uint4*)P, row_ptr, esrc, attn1, (uint4*)Q);

    gat_gemm2_r25<<<(NN + 63) / 64, 256, 0, stream>>>(Q, W2t, b2, P);
    gat_attn8_r25<<<NN / 4, 256, 0, stream>>>((const uint4*)P, row_ptr, esrc, attn2, (uint4*)Q);

    gat_gemm64_r25<<<dim3((NN + 63) / 64, 1), 256, 0, stream>>>(Q, W3t, b3, h3, NN, 256, 64);
    gat_attn1_r25<<<A1_BLOCKS, 256, 0, stream>>>((const uint4*)h3, row_ptr, esrc, attn3, blockmax);

    gat_final_r25<<<1, 1024, 0, stream>>>(blockmax, out);
}

// Round 9
// 363.056 us; speedup vs baseline: 1.1506x; 1.1114x over previous
//
#include <hip/hip_runtime.h>
#include <hip/hip_bf16.h>

typedef unsigned int u32;
typedef unsigned short u16;
typedef _Float16 f16x2 __attribute__((ext_vector_type(2)));
typedef _Float16 f16x8 __attribute__((ext_vector_type(8)));
typedef float f32x4 __attribute__((ext_vector_type(4)));

#define NN 50000
#define EE 800000
#define SCAN_B ((NN + 255) / 256)     // 196
#define G1_TILES (((NN + 63) / 64) * 2)   // 1564 gemm1 blocks (BN=128, Nc=256)
#define CNT_B ((EE + 255) / 256)      // 3125 count blocks
#define A1_ROWS ((NN + 3) / 4)        // 12500 attn1 blocks (1 node per wave)
#define F1_B 64
#define F1_PER ((A1_ROWS + F1_B - 1) / F1_B)  // 196 rows per stage-1 block

__device__ __forceinline__ f16x2 ash(u32 u) { union { u32 u; f16x2 h; } c; c.u = u; return c.h; }
__device__ __forceinline__ u32 h2u(f16x2 h) { union { u32 u; f16x2 h; } c; c.h = h; return c.u; }
__device__ __forceinline__ u16 f2h(float v) { _Float16 h = (_Float16)v; return *(u16*)&h; }
__device__ __forceinline__ u32 pack2h(float a, float b) {
    return (u32)f2h(a) | ((u32)f2h(b) << 16);
}
__device__ __forceinline__ float elu(float v) { return v > 0.f ? v : __expf(v) - 1.f; }

// ---------------- prep: weight transpose->f16 (blocks 0-575) + deg zero (blocks 576+) ----------------

__global__ __launch_bounds__(256) void gat_prep_r26(const float* __restrict__ W1,
                                                    const float* __restrict__ W2,
                                                    const float* __restrict__ W3,
                                                    u16* __restrict__ W1t,
                                                    u16* __restrict__ W2t,
                                                    u16* __restrict__ W3t,
                                                    int* __restrict__ deg) {
    int b = blockIdx.x, t = threadIdx.x;
    if (b < 256) {
        if (t < 128) W1t[(long)b * 128 + t] = f2h(W1[(long)t * 256 + b]);
    } else if (b < 512) {
        int n = b - 256;
        W2t[(long)n * 256 + t] = f2h(W2[(long)t * 256 + n]);
    } else if (b < 576) {
        int n = b - 512;
        W3t[(long)n * 256 + t] = f2h(W3[(long)t * 64 + n]);
    } else {
        int i = (b - 576) * 256 + t;
        if (i < NN) deg[i] = 0;
    }
}

// ---------------- MFMA GEMM BN=128 body (layer-1 fused kernel) ----------------

template <int AHF>
__device__ __forceinline__ void gemm128_body(const void* __restrict__ Ain,
                                             const u16* __restrict__ Wt,
                                             const float* __restrict__ bias,
                                             u16* __restrict__ C,
                                             int M, int K, int Nc,
                                             int bm, int bn) {
    __shared__ __align__(16) u16 As[64 * 40];
    __shared__ __align__(16) u16 Bs[128 * 40];
    const int t    = threadIdx.x;
    const int w    = t >> 6;
    const int lane = t & 63;
    const int sm   = t >> 2;
    const int sk   = (t & 3) * 8;
    const int fq   = (lane >> 4) * 8;
    const int fr   = lane & 15;
    const int nbase = w * 32;

    f32x4 acc[4][2] = {};

    for (int k0 = 0; k0 < K; k0 += 32) {
        {
            int gr = bm + sm;
            f16x8 av = {};
            if (gr < M) {
                if (AHF) {
                    av = *(const f16x8*)((const u16*)Ain + (long)gr * K + k0 + sk);
                } else {
                    const float* p = (const float*)Ain + (long)gr * K + k0 + sk;
                    #pragma unroll
                    for (int i = 0; i < 8; ++i) av[i] = (_Float16)p[i];
                }
            }
            *(f16x8*)&As[sm * 40 + sk] = av;
        }
        #pragma unroll
        for (int i = 0; i < 2; ++i) {
            int tau = t + i * 256;
            int row = tau >> 2, ck = (tau & 3) * 8;
            f16x8 bv = *(const f16x8*)(Wt + (long)(bn + row) * K + k0 + ck);
            *(f16x8*)&Bs[row * 40 + ck] = bv;
        }
        __syncthreads();
        f16x8 afr[4], bfr[2];
        #pragma unroll
        for (int mt = 0; mt < 4; ++mt)
            afr[mt] = *(const f16x8*)&As[(mt * 16 + fr) * 40 + fq];
        #pragma unroll
        for (int nt = 0; nt < 2; ++nt)
            bfr[nt] = *(const f16x8*)&Bs[(nbase + nt * 16 + fr) * 40 + fq];
        #pragma unroll
        for (int mt = 0; mt < 4; ++mt)
            #pragma unroll
            for (int nt = 0; nt < 2; ++nt)
                acc[mt][nt] = __builtin_amdgcn_mfma_f32_16x16x32_f16(
                    afr[mt], bfr[nt], acc[mt][nt], 0, 0, 0);
        __syncthreads();
    }
    #pragma unroll
    for (int mt = 0; mt < 4; ++mt) {
        #pragma unroll
        for (int r = 0; r < 4; ++r) {
            int row = bm + mt * 16 + (lane >> 4) * 4 + r;
            if (row >= M) continue;
            #pragma unroll
            for (int nt = 0; nt < 2; ++nt) {
                int col = bn + nbase + nt * 16 + fr;
                C[(long)row * Nc + col] = f2h(acc[mt][nt][r] + bias[col]);
            }
        }
    }
}

// ---------------- fused: layer-1 GEMM + degree count (independent, concurrent) ----------------

__global__ __launch_bounds__(256) void gat_fuse1_r26(const float* __restrict__ x,
                                                     const u16* __restrict__ W1t,
                                                     const float* __restrict__ b1,
                                                     u16* __restrict__ P,
                                                     const int* __restrict__ dst,
                                                     int* __restrict__ deg) {
    int b = blockIdx.x;
    if (b < G1_TILES) {
        int bm = (b >> 1) * 64;
        int bn = (b & 1) * 128;
        gemm128_body<0>(x, W1t, b1, P, NN, 128, 256, bm, bn);
    } else {
        int e = (b - G1_TILES) * 256 + threadIdx.x;
        if (e < EE) atomicAdd(&deg[dst[e]], 1);
    }
}

// ---------------- layer-2 GEMM: BM=64 x BN=256 single pass (A read once; neutral-to-better) -------

__global__ __launch_bounds__(256) void gat_gemm2_r26(const u16* __restrict__ Q,
                                                     const u16* __restrict__ W2t,
                                                     const float* __restrict__ b2,
                                                     u16* __restrict__ P) {
    __shared__ __align__(16) u16 As[64 * 40];
    __shared__ __align__(16) u16 Bs[256 * 40];
    const int t    = threadIdx.x;
    const int w    = t >> 6;
    const int lane = t & 63;
    const int sm   = t >> 2;
    const int sk   = (t & 3) * 8;
    const int fq   = (lane >> 4) * 8;
    const int fr   = lane & 15;
    const int nbase = w * 64;
    const int bm   = blockIdx.x * 64;

    f32x4 acc[4][4] = {};

    for (int k0 = 0; k0 < 256; k0 += 32) {
        {
            int gr = bm + sm;
            f16x8 av = {};
            if (gr < NN) av = *(const f16x8*)(Q + (long)gr * 256 + k0 + sk);
            *(f16x8*)&As[sm * 40 + sk] = av;
        }
        #pragma unroll
        for (int i = 0; i < 4; ++i) {
            int tau = t + i * 256;
            int row = tau >> 2, ck = (tau & 3) * 8;
            f16x8 bv = *(const f16x8*)(W2t + (long)row * 256 + k0 + ck);
            *(f16x8*)&Bs[row * 40 + ck] = bv;
        }
        __syncthreads();
        f16x8 afr[4], bfr[4];
        #pragma unroll
        for (int mt = 0; mt < 4; ++mt)
            afr[mt] = *(const f16x8*)&As[(mt * 16 + fr) * 40 + fq];
        #pragma unroll
        for (int nt = 0; nt < 4; ++nt)
            bfr[nt] = *(const f16x8*)&Bs[(nbase + nt * 16 + fr) * 40 + fq];
        #pragma unroll
        for (int mt = 0; mt < 4; ++mt)
            #pragma unroll
            for (int nt = 0; nt < 4; ++nt)
                acc[mt][nt] = __builtin_amdgcn_mfma_f32_16x16x32_f16(
                    afr[mt], bfr[nt], acc[mt][nt], 0, 0, 0);
        __syncthreads();
    }
    #pragma unroll
    for (int mt = 0; mt < 4; ++mt) {
        #pragma unroll
        for (int r = 0; r < 4; ++r) {
            int row = bm + mt * 16 + (lane >> 4) * 4 + r;
            if (row >= NN) continue;
            #pragma unroll
            for (int nt = 0; nt < 4; ++nt) {
                int col = nbase + nt * 16 + fr;
                P[(long)row * 256 + col] = f2h(acc[mt][nt][r] + b2[col]);
            }
        }
    }
}

// ---------------- CSR scan + scatter ----------------

__global__ __launch_bounds__(256) void gat_scana_r26(const int* __restrict__ deg,
                                                     int* __restrict__ bsum) {
    __shared__ int s[256];
    int t = threadIdx.x;
    int i = blockIdx.x * 256 + t;
    s[t] = (i < NN) ? deg[i] : 0;
    __syncthreads();
    for (int o = 128; o > 0; o >>= 1) {
        if (t < o) s[t] += s[t + o];
        __syncthreads();
    }
    if (t == 0) bsum[blockIdx.x] = s[0];
}

__global__ __launch_bounds__(256) void gat_scanc_r26(const int* __restrict__ deg,
                                                     const int* __restrict__ bsum,
                                                     int* __restrict__ row_ptr,
                                                     int* __restrict__ cursor) {
    __shared__ int sb[256];
    __shared__ int s[256];
    int t = threadIdx.x;
    sb[t] = (t < SCAN_B) ? bsum[t] : 0;
    __syncthreads();
    for (int o = 1; o < 256; o <<= 1) {
        int u = (t >= o) ? sb[t - o] : 0;
        __syncthreads();
        sb[t] += u;
        __syncthreads();
    }
    int boff = (blockIdx.x == 0) ? 0 : sb[blockIdx.x - 1];
    if (blockIdx.x == 0 && t == 0) row_ptr[NN] = sb[SCAN_B - 1];
    int i = blockIdx.x * 256 + t;
    int v = (i < NN) ? deg[i] : 0;
    s[t] = v;
    __syncthreads();
    for (int o = 1; o < 256; o <<= 1) {
        int u = (t >= o) ? s[t - o] : 0;
        __syncthreads();
        s[t] += u;
        __syncthreads();
    }
    if (i < NN) {
        int excl = s[t] - v + boff;
        row_ptr[i] = excl;
        cursor[i]  = excl;
    }
}

__global__ void gat_scatter_r26(const int* __restrict__ src, const int* __restrict__ dst,
                                int* __restrict__ cursor, int* __restrict__ esrc) {
    int e = blockIdx.x * 256 + threadIdx.x;
    if (e < EE) {
        int pos = atomicAdd(&cursor[dst[e]], 1);
        esrc[pos] = src[e];
    }
}

// ---------------- MFMA GEMM, BN=64 — layer 3 (Nc=64) ----------------

__global__ __launch_bounds__(256) void gat_gemm64_r26(const u16* __restrict__ Ain,
                                                      const u16* __restrict__ Wt,
                                                      const float* __restrict__ bias,
                                                      u16* __restrict__ C,
                                                      int M, int K, int Nc) {
    __shared__ __align__(16) u16 As[64 * 40];
    __shared__ __align__(16) u16 Bs[64 * 40];
    const int t    = threadIdx.x;
    const int bm   = blockIdx.x * 64;
    const int bn   = blockIdx.y * 64;
    const int w    = t >> 6;
    const int lane = t & 63;
    const int sm   = t >> 2;
    const int sk   = (t & 3) * 8;
    const int mbase = (w & 1) * 32;
    const int nbase = (w >> 1) * 32;
    const int fq    = (lane >> 4) * 8;
    const int fr    = lane & 15;

    f32x4 acc[2][2] = {};

    for (int k0 = 0; k0 < K; k0 += 32) {
        {
            int gr = bm + sm;
            f16x8 av = {};
            if (gr < M) av = *(const f16x8*)(Ain + (long)gr * K + k0 + sk);
            *(f16x8*)&As[sm * 40 + sk] = av;
        }
        {
            f16x8 bv = *(const f16x8*)(Wt + (long)(bn + sm) * K + k0 + sk);
            *(f16x8*)&Bs[sm * 40 + sk] = bv;
        }
        __syncthreads();
        f16x8 afr[2], bfr[2];
        #pragma unroll
        for (int mt = 0; mt < 2; ++mt)
            afr[mt] = *(const f16x8*)&As[(mbase + mt * 16 + fr) * 40 + fq];
        #pragma unroll
        for (int nt = 0; nt < 2; ++nt)
            bfr[nt] = *(const f16x8*)&Bs[(nbase + nt * 16 + fr) * 40 + fq];
        #pragma unroll
        for (int mt = 0; mt < 2; ++mt)
            #pragma unroll
            for (int nt = 0; nt < 2; ++nt)
                acc[mt][nt] = __builtin_amdgcn_mfma_f32_16x16x32_f16(
                    afr[mt], bfr[nt], acc[mt][nt], 0, 0, 0);
        __syncthreads();
    }
    #pragma unroll
    for (int mt = 0; mt < 2; ++mt) {
        #pragma unroll
        for (int r = 0; r < 4; ++r) {
            int row = bm + mbase + mt * 16 + (lane >> 4) * 4 + r;
            if (row >= M) continue;
            #pragma unroll
            for (int nt = 0; nt < 2; ++nt) {
                int col = bn + nbase + nt * 16 + fr;
                C[(long)row * Nc + col] = f2h(acc[mt][nt][r] + bias[col]);
            }
        }
    }
}

// ---------------- Attention layers 1&2: half-wave pairing, phase-split gathers (r23-exact) ---------
// Banked optimum for this kernel: cross-batch pipelining refuted 3x (spill @8w, occupancy @6w).

__global__ __launch_bounds__(256, 8) void gat_attn8_r26(const uint4* __restrict__ h4,
                                                        const int* __restrict__ row_ptr,
                                                        const int* __restrict__ esrc,
                                                        const float* __restrict__ attn,
                                                        uint4* __restrict__ act4) {
    int t = threadIdx.x;
    int lane = t & 63, wv = t >> 6;
    int hf = lane >> 5, sub = lane & 31;
    int li = lane & 7;
    int n = blockIdx.x * 4 + wv;          // grid = NN/4 exactly
    float4 av0 = ((const float4*)attn)[sub * 2];
    float4 av1 = ((const float4*)attn)[sub * 2 + 1];
    f16x2 aw0 = {(_Float16)av0.x, (_Float16)av0.y};
    f16x2 aw1 = {(_Float16)av0.z, (_Float16)av0.w};
    f16x2 aw2 = {(_Float16)av1.x, (_Float16)av1.y};
    f16x2 aw3 = {(_Float16)av1.z, (_Float16)av1.w};
    const f16x2 c02 = {(_Float16)0.2f, (_Float16)0.2f};
    uint4 ud = h4[(long)n * 32 + sub];
    f16x2 hd0 = ash(ud.x), hd1 = ash(ud.y), hd2 = ash(ud.z), hd3 = ash(ud.w);
    int lo = __builtin_amdgcn_readfirstlane(row_ptr[n]);
    int hi = __builtin_amdgcn_readfirstlane(row_ptr[n + 1]);
    int clampv = hi - 1;                  // every node has >=1 in-edge
    float l = 0.f;
    f16x2 O0 = {}, O1 = {}, O2 = {}, O3 = {};
    int e = lo;
    int ia0 = lo + li;
    int myidx = esrc[ia0 < clampv ? ia0 : clampv];
    // ---- full batches of 8 edges ----
    for (; e + 8 <= hi; e += 8) {
        int ia = e + 8 + li;
        int nextidx = esrc[ia < clampv ? ia : clampv];
        // phase 1: all four source rows (independent shfls)
        int srow[4];
        #pragma unroll
        for (int j2 = 0; j2 < 4; ++j2) srow[j2] = __shfl(myidx, 2 * j2 + hf, 8);
        // phase 2: all four gathers in flight
        uint4 u[4];
        #pragma unroll
        for (int j2 = 0; j2 < 4; ++j2) u[j2] = h4[(long)srow[j2] * 32 + sub];
        // phase 3: compute
        #pragma unroll
        for (int j2 = 0; j2 < 4; ++j2) {
            f16x2 x0 = ash(u[j2].x), x1 = ash(u[j2].y), x2 = ash(u[j2].z), x3 = ash(u[j2].w);
            f16x2 v0 = x0 + hd0, v1 = x1 + hd1, v2 = x2 + hd2, v3 = x3 + hd3;
            f16x2 r0 = __builtin_elementwise_max(v0, v0 * c02);
            f16x2 r1 = __builtin_elementwise_max(v1, v1 * c02);
            f16x2 r2 = __builtin_elementwise_max(v2, v2 * c02);
            f16x2 r3 = __builtin_elementwise_max(v3, v3 * c02);
            f16x2 acc = r0 * aw0;
            acc += r1 * aw1;
            acc += r2 * aw2;
            acc += r3 * aw3;
            float p = (float)acc.x + (float)acc.y;
            p += __shfl_xor(p, 1);
            p += __shfl_xor(p, 2);
            float w = __expf(p);
            l += w;
            _Float16 wh = (_Float16)w;
            f16x2 w2 = {wh, wh};
            O0 += x0 * w2; O1 += x1 * w2; O2 += x2 * w2; O3 += x3 * w2;
        }
        myidx = nextidx;
    }
    // ---- tail 0..7 edges: validity-masked pairs ----
    for (int j = 0; e + j < hi; j += 2) {
        int srow = __shfl(myidx, j + hf, 8);
        uint4 u = h4[(long)srow * 32 + sub];
        f16x2 x0 = ash(u.x), x1 = ash(u.y), x2 = ash(u.z), x3 = ash(u.w);
        f16x2 v0 = x0 + hd0, v1 = x1 + hd1, v2 = x2 + hd2, v3 = x3 + hd3;
        f16x2 r0 = __builtin_elementwise_max(v0, v0 * c02);
        f16x2 r1 = __builtin_elementwise_max(v1, v1 * c02);
        f16x2 r2 = __builtin_elementwise_max(v2, v2 * c02);
        f16x2 r3 = __builtin_elementwise_max(v3, v3 * c02);
        f16x2 acc = r0 * aw0;
        acc += r1 * aw1;
        acc += r2 * aw2;
        acc += r3 * aw3;
        float p = (float)acc.x + (float)acc.y;
        p += __shfl_xor(p, 1);
        p += __shfl_xor(p, 2);
        float w = (e + j + hf < hi) ? __expf(p) : 0.f;
        l += w;
        _Float16 wh = (_Float16)w;
        f16x2 w2 = {wh, wh};
        O0 += x0 * w2; O1 += x1 * w2; O2 += x2 * w2; O3 += x3 * w2;
    }
    // merge halves
    l += __shfl_xor(l, 32);
    O0 += ash(__shfl_xor((int)h2u(O0), 32));
    O1 += ash(__shfl_xor((int)h2u(O1), 32));
    O2 += ash(__shfl_xor((int)h2u(O2), 32));
    O3 += ash(__shfl_xor((int)h2u(O3), 32));
    float rinv = 1.f / l;
    if (hf == 0) {
        uint4 outv;
        outv.x = pack2h(elu((float)O0.x * rinv), elu((float)O0.y * rinv));
        outv.y = pack2h(elu((float)O1.x * rinv), elu((float)O1.y * rinv));
        outv.z = pack2h(elu((float)O2.x * rinv), elu((float)O2.y * rinv));
        outv.w = pack2h(elu((float)O3.x * rinv), elu((float)O3.y * rinv));
        act4[(long)n * 32 + sub] = outv;
    }
}

// ---------------- Attention layer 3: 1 node/wave, 8-lane groups, 8 edges in flight -----------------
// r26: attn8's proven decomposition (1 node per wave, 50000 waves) instead of 16384 grid-stride
// waves: 3x the TLP for identical latency-bound work. Per-block max over 4 waves -> blockmax row.

__global__ __launch_bounds__(256) void gat_attn1_r26(const uint4* __restrict__ h4,
                                                     const int* __restrict__ row_ptr,
                                                     const int* __restrict__ esrc,
                                                     const float* __restrict__ attn,
                                                     float* __restrict__ blockmax) {
    int t = threadIdx.x;
    int lane = t & 63, wv = t >> 6;
    int g = lane >> 3, sub = lane & 7;    // 8 groups of 8 lanes; lane sub holds cols 8*sub..8*sub+7
    int n = blockIdx.x * 4 + wv;          // grid = NN/4 exactly
    float4 aq0 = ((const float4*)attn)[sub * 2];
    float4 aq1 = ((const float4*)attn)[sub * 2 + 1];
    f16x2 aw0 = {(_Float16)aq0.x, (_Float16)aq0.y};
    f16x2 aw1 = {(_Float16)aq0.z, (_Float16)aq0.w};
    f16x2 aw2 = {(_Float16)aq1.x, (_Float16)aq1.y};
    f16x2 aw3 = {(_Float16)aq1.z, (_Float16)aq1.w};
    const f16x2 c02 = {(_Float16)0.2f, (_Float16)0.2f};
    uint4 ud = h4[(long)n * 8 + sub];
    f16x2 hd0 = ash(ud.x), hd1 = ash(ud.y), hd2 = ash(ud.z), hd3 = ash(ud.w);
    int lo = row_ptr[n], hi = row_ptr[n + 1];
    float l = 0.f;
    f16x2 O0 = {}, O1 = {}, O2 = {}, O3 = {};
    int eg = lo + g;
    int s = esrc[(eg < hi) ? eg : hi - 1];
    uint4 ucur = h4[(long)s * 8 + sub];              // iter-0 row in flight
    for (int e = lo; e < hi; e += 8) {
        int egn = e + 8 + g;
        int snext = esrc[(egn < hi) ? egn : hi - 1];
        bool more = (e + 8 < hi);
        uint4 unext = {};
        if (more) unext = h4[(long)snext * 8 + sub]; // next-iter row issued before compute
        bool valid = e + g < hi;
        f16x2 x0 = ash(ucur.x), x1 = ash(ucur.y), x2 = ash(ucur.z), x3 = ash(ucur.w);
        f16x2 v0 = x0 + hd0, v1 = x1 + hd1, v2 = x2 + hd2, v3 = x3 + hd3;
        f16x2 r0 = __builtin_elementwise_max(v0, v0 * c02);
        f16x2 r1 = __builtin_elementwise_max(v1, v1 * c02);
        f16x2 r2 = __builtin_elementwise_max(v2, v2 * c02);
        f16x2 r3 = __builtin_elementwise_max(v3, v3 * c02);
        f16x2 acc = r0 * aw0;
        acc += r1 * aw1;
        acc += r2 * aw2;
        acc += r3 * aw3;
        float p = (float)acc.x + (float)acc.y;
        p += __shfl_xor(p, 1);
        p += __shfl_xor(p, 2);
        p += __shfl_xor(p, 4);
        float w = valid ? __expf(p) : 0.f;
        l += w;
        _Float16 wh = (_Float16)w;
        f16x2 w2 = {wh, wh};
        O0 += x0 * w2; O1 += x1 * w2; O2 += x2 * w2; O3 += x3 * w2;
        if (more) ucur = unext;
    }
    // merge 8 groups (levels 8,16,32)
    l += __shfl_xor(l, 8); l += __shfl_xor(l, 16); l += __shfl_xor(l, 32);
    O0 += ash(__shfl_xor((int)h2u(O0), 8));
    O0 += ash(__shfl_xor((int)h2u(O0), 16));
    O0 += ash(__shfl_xor((int)h2u(O0), 32));
    O1 += ash(__shfl_xor((int)h2u(O1), 8));
    O1 += ash(__shfl_xor((int)h2u(O1), 16));
    O1 += ash(__shfl_xor((int)h2u(O1), 32));
    O2 += ash(__shfl_xor((int)h2u(O2), 8));
    O2 += ash(__shfl_xor((int)h2u(O2), 16));
    O2 += ash(__shfl_xor((int)h2u(O2), 32));
    O3 += ash(__shfl_xor((int)h2u(O3), 8));
    O3 += ash(__shfl_xor((int)h2u(O3), 16));
    O3 += ash(__shfl_xor((int)h2u(O3), 32));
    float rinv = 1.f / l;
    __shared__ float sm[4][64];
    if (g == 0) {
        sm[wv][sub * 8 + 0] = (float)O0.x * rinv; sm[wv][sub * 8 + 1] = (float)O0.y * rinv;
        sm[wv][sub * 8 + 2] = (float)O1.x * rinv; sm[wv][sub * 8 + 3] = (float)O1.y * rinv;
        sm[wv][sub * 8 + 4] = (float)O2.x * rinv; sm[wv][sub * 8 + 5] = (float)O2.y * rinv;
        sm[wv][sub * 8 + 6] = (float)O3.x * rinv; sm[wv][sub * 8 + 7] = (float)O3.y * rinv;
    }
    __syncthreads();
    if (wv == 0) {
        float r = sm[0][lane];
        #pragma unroll
        for (int i = 1; i < 4; ++i) r = fmaxf(r, sm[i][lane]);
        blockmax[(long)blockIdx.x * 64 + lane] = r;
    }
}

// ---------------- hierarchical max-pool: 12500 rows -> 64 -> 1 ----------------

__global__ __launch_bounds__(256) void gat_final1_r26(const float* __restrict__ blockmax,
                                                      float* __restrict__ partial) {
    int t = threadIdx.x;
    int lane = t & 63, wv = t >> 6;
    int r0 = blockIdx.x * F1_PER;
    int r1 = r0 + F1_PER; if (r1 > A1_ROWS) r1 = A1_ROWS;
    float v = -1e30f;
    for (int r = r0 + wv; r < r1; r += 4)
        v = fmaxf(v, blockmax[(long)r * 64 + lane]);
    __shared__ float sm[4][64];
    sm[wv][lane] = v;
    __syncthreads();
    if (wv == 0) {
        float r = sm[0][lane];
        #pragma unroll
        for (int i = 1; i < 4; ++i) r = fmaxf(r, sm[i][lane]);
        partial[(long)blockIdx.x * 64 + lane] = r;
    }
}

__global__ __launch_bounds__(256) void gat_final2_r26(const float* __restrict__ partial,
                                                      float* __restrict__ out) {
    int t = threadIdx.x;
    int lane = t & 63, wv = t >> 6;
    float v = -1e30f;
    for (int r = wv; r < F1_B; r += 4)
        v = fmaxf(v, partial[(long)r * 64 + lane]);
    __shared__ float sm[4][64];
    sm[wv][lane] = v;
    __syncthreads();
    if (wv == 0) {
        float r = sm[0][lane];
        #pragma unroll
        for (int i = 1; i < 4; ++i) r = fmaxf(r, sm[i][lane]);
        out[lane] = r;
    }
}

// ---------------- launch ----------------

extern "C" void kernel_launch(void* const* d_in, const int* in_sizes, int n_in,
                              void* d_out, int out_size, void* d_ws, size_t ws_size,
                              hipStream_t stream) {
    const float* x     = (const float*)d_in[0];
    const int*   src   = (const int*)  d_in[1];
    const int*   dst   = (const int*)  d_in[2];
    const float* W1    = (const float*)d_in[3];
    const float* b1    = (const float*)d_in[4];
    const float* attn1 = (const float*)d_in[5];
    const float* W2    = (const float*)d_in[6];
    const float* b2    = (const float*)d_in[7];
    const float* attn2 = (const float*)d_in[8];
    const float* W3    = (const float*)d_in[9];
    const float* b3    = (const float*)d_in[10];
    const float* attn3 = (const float*)d_in[11];
    float* out = (float*)d_out;

    char* ws = (char*)d_ws;
    size_t off = 0;
    auto carve = [&](size_t bytes) { void* p = ws + off; off += (bytes + 255) & ~size_t(255); return p; };
    u16*   P        = (u16*)  carve((size_t)NN * 256 * 2);
    u16*   Q        = (u16*)  carve((size_t)NN * 256 * 2);
    u16*   h3       = (u16*)  carve((size_t)NN * 64 * 2);
    int*   row_ptr  = (int*)  carve((size_t)(NN + 1) * 4);
    int*   deg      = (int*)  carve((size_t)NN * 4);
    int*   cursor   = (int*)  carve((size_t)NN * 4);
    int*   esrc     = (int*)  carve((size_t)EE * 4);
    float* blockmax = (float*)carve((size_t)A1_ROWS * 64 * 4);
    float* partial  = (float*)carve((size_t)F1_B * 64 * 4);
    int*   bsum     = (int*)  carve((size_t)SCAN_B * 4);
    u16*   W1t      = (u16*)  carve((size_t)256 * 128 * 2);
    u16*   W2t      = (u16*)  carve((size_t)256 * 256 * 2);
    u16*   W3t      = (u16*)  carve((size_t)64 * 256 * 2);

    gat_prep_r26<<<576 + SCAN_B, 256, 0, stream>>>(W1, W2, W3, W1t, W2t, W3t, deg);
    gat_fuse1_r26<<<G1_TILES + CNT_B, 256, 0, stream>>>(x, W1t, b1, P, dst, deg);
    gat_scana_r26<<<SCAN_B, 256, 0, stream>>>(deg, bsum);
    gat_scanc_r26<<<SCAN_B, 256, 0, stream>>>(deg, bsum, row_ptr, cursor);
    gat_scatter_r26<<<CNT_B, 256, 0, stream>>>(src, dst, cursor, esrc);

    gat_attn8_r26<<<NN / 4, 256, 0, stream>>>((const uint4*)P, row_ptr, esrc, attn1, (uint4*)Q);

    gat_gemm2_r26<<<(NN + 63) / 64, 256, 0, stream>>>(Q, W2t, b2, P);
    gat_attn8_r26<<<NN / 4, 256, 0, stream>>>((const uint4*)P, row_ptr, esrc, attn2, (uint4*)Q);

    gat_gemm64_r26<<<dim3((NN + 63) / 64, 1), 256, 0, stream>>>(Q, W3t, b3, h3, NN, 256, 64);
    gat_attn1_r26<<<A1_ROWS, 256, 0, stream>>>((const uint4*)h3, row_ptr, esrc, attn3, blockmax);

    gat_final1_r26<<<F1_B, 256, 0, stream>>>(blockmax, partial);
    gat_final2_r26<<<1, 256, 0, stream>>>(partial, out);
}